// Round 11
// baseline (1590.045 us; speedup 1.0000x reference)
//
#include <hip/hip_runtime.h>
#include <math.h>

#define T_   32
#define N_   64
#define NL   64
#define E_   128
#define G3   384   // 3*E
#define NE   4
#define CH   64
#define D_   16
#define HW   16
#define RH   64
#define LE   64
#define HD   512
#define A_   16
#define INVN 32
#define KCOLS 9216 // CH*D_*3*3
#define OUTW 663
#define OXP  24         // obs LDS x-pitch (halves)
#define OROW 456        // 18*OXP + 24 pad (y-stride 228 dw = 4 mod 32 -> 2-way)
#define OPL  8664       // 19 * OROW
#define KPITCH 168      // padded kern row pitch per channel (144 real + 24 pad)

typedef _Float16 half8 __attribute__((ext_vector_type(8)));
typedef _Float16 half4 __attribute__((ext_vector_type(4)));
typedef float floatx4 __attribute__((ext_vector_type(4)));

__device__ __forceinline__ float fsig(float x)  { return __builtin_amdgcn_rcpf(1.f + __expf(-x)); }
__device__ __forceinline__ float ftanh(float x) { return 1.f - 2.f*__builtin_amdgcn_rcpf(1.f + __expf(2.f*x)); }

// ---------------- merged prep 1: M, wiT4, WBpack, invpa, flags-zero, kernel_wT perm --
__global__ __launch_bounds__(256) void k_prep1(
    const int* lines, const float* emb_task, float* M,
    const float* wif, const float* wib, float* wiT4,
    const float* whf, const float* whb, _Float16* WBpack,
    const float* inv, const float* inv_w, const float* inv_b,
    const int* pa, const float* emb_lower, float* inv_all, float* pa_all,
    int* flags, const float* kernel_w, float* kernel_wpT) {
    int b = blockIdx.x, tid = threadIdx.x;
    __shared__ float Tt[128][149];     // transpose tile (only used by b>=2161)
    if (b < 1024) {                    // M: emb-bag sum
        #pragma unroll
        for (int r = 0; r < 2; ++r) {
            int idx = b*512 + r*256 + tid;
            int nl = idx >> 7, i = idx & 127;
            const int* ln = lines + nl*4;
            float s = 0.f;
            #pragma unroll
            for (int t = 0; t < 4; ++t) s += emb_task[ln[t]*E_ + i];
            M[nl*E_ + i] = s;
        }
    } else if (b < 1408) {             // wiT4 repack
        int ob = (b - 1024)*2 + (tid >> 7);
        int g = ob % 384, dir = ob / 384;
        int k = tid & 127;
        const float* wi = dir ? wib : wif;
        int dst = ((dir*32 + (k>>2))*384 + g)*4 + (k&3);
        wiT4[dst] = wi[g*128 + k];
    } else if (b < 1504) {             // WBpack fp16 hi/lo fragments
        int ob = (b - 1408)*4 + (tid >> 6);
        int lane = tid & 63;
        int nt = ob % 6; int rest = ob / 6;
        int term = rest % 2; rest /= 2;
        int kt = rest % 4; rest /= 4;
        int w = rest % 4; int dir = rest / 4;
        const float* wh = dir ? whb : whf;
        int gt = nt >> 1, isub = nt & 1;
        int g  = gt*128 + w*32 + isub*16 + (lane & 15);
        int k0 = kt*32 + (lane >> 4)*8;
        _Float16* dst = WBpack + (size_t)ob*512 + lane*8;
        #pragma unroll
        for (int e = 0; e < 8; ++e) {
            float v = wh[g*128 + k0 + e];
            _Float16 hi = (_Float16)v;
            dst[e] = (term == 0) ? hi : (_Float16)(v - (float)hi);
        }
    } else if (b < 2016) {             // inv relu + pa emb-bag
        int tn = (b - 1504)*4 + (tid >> 6);
        int r = tid & 63;
        const float* iv = inv + tn*INVN;
        float acc = inv_b[r];
        #pragma unroll
        for (int i = 0; i < INVN; ++i) acc += iv[i]*inv_w[i*RH + r];
        inv_all[tn*RH + r] = fmaxf(acc, 0.f);
        const int* pp = pa + tn*4;
        float s = 0.f;
        #pragma unroll
        for (int j = 0; j < 4; ++j) s += emb_lower[pp[j]*LE + r];
        pa_all[tn*LE + r] = s;
    } else if (b < 2161) {             // zero legacy flags
        int idx = (b - 2016)*256 + tid;
        if (idx < 36992) flags[idx] = 0;
    } else {                           // per-channel coalesced transpose (64 blocks)
        int c = b - 2161;              // 0..63
        for (int idx = tid; idx < 128*144; idx += 256) {
            int r = idx / 144, q = idx - r*144;
            Tt[r][q] = kernel_w[(size_t)r*KCOLS + c*144 + q];
        }
        __syncthreads();
        for (int idx = tid; idx < 144*128; idx += 256) {
            int cl = idx >> 7, k = idx & 127;   // cl = ta*16+d (permuted local col)
            int ta = cl >> 4, d = cl & 15;
            kernel_wpT[(size_t)(c*144 + cl)*E_ + k] = Tt[k][d*9 + ta];
        }
    }
}

// ---------------- fused mid kernel: prep2 | kern_all(MFMA) | giM -------------------
__global__ __launch_bounds__(256) void k_mid(
    const float* M, const float* inv_all, const float* pa_all,
    const float* zw, const float* zb,
    const float* uw, const float* ub, const float* dw, const float* db,
    const int* p0, int* p_arr, int* pflag,
    float* zmp, float* zip, float* ump, float* dmp, float* uip, float* dip,
    const float* kernel_wpT, const float* kernel_b, unsigned int* kernu,
    const float* wiT4, const float* bif, const float* bib, float* giM) {
    int b = blockIdx.x, tid = threadIdx.x;
    if (b < 481) {
        // ---------------- prep2 (identical arithmetic) ----------------
        if (b < 256) {                     // zmp = M @ zw[0:128]
            int cb = b & 1, rb = b >> 1;
            __shared__ float At[32][E_];
            for (int idx = tid; idx < 32*E_; idx += 256) {
                int r = idx >> 7, k = idx & 127;
                At[r][k] = M[(rb*32 + r)*E_ + k];
            }
            __syncthreads();
            float acc[32];
            #pragma unroll
            for (int r = 0; r < 32; ++r) acc[r] = 0.f;
            int col = cb*256 + tid;
            #pragma unroll 4
            for (int k = 0; k < E_; ++k) {
                float w = zw[k*HD + col];
                #pragma unroll
                for (int r = 0; r < 32; ++r) acc[r] += At[r][k]*w;
            }
            #pragma unroll
            for (int r = 0; r < 32; ++r)
                zmp[(size_t)(rb*32 + r)*HD + col] = acc[r];
        } else if (b < 384) {              // zip = [inv|pa] @ zw[192:320] + zb
            int b2 = b - 256;
            int cb = b2 & 1, rb = b2 >> 1;
            __shared__ float At2[32][E_];
            for (int idx = tid; idx < 32*E_; idx += 256) {
                int r = idx >> 7, k = idx & 127;
                int row = rb*32 + r;
                At2[r][k] = (k < 64) ? inv_all[row*RH + k] : pa_all[row*LE + (k - 64)];
            }
            __syncthreads();
            float acc[32];
            #pragma unroll
            for (int r = 0; r < 32; ++r) acc[r] = 0.f;
            int col = cb*256 + tid;
            #pragma unroll 4
            for (int k = 0; k < E_; ++k) {
                float w = zw[(192 + k)*HD + col];
                #pragma unroll
                for (int r = 0; r < 32; ++r) acc[r] += At2[r][k]*w;
            }
            float bb = zb[col];
            #pragma unroll
            for (int r = 0; r < 32; ++r)
                zip[(size_t)(rb*32 + r)*HD + col] = acc[r] + bb;
        } else if (b < 448) {              // ump/dmp from M
            int wg = b - 384;
            __shared__ float Mt[64][E_];
            for (int idx = tid; idx < 64*E_; idx += 256)
                ((float*)Mt)[idx] = M[(size_t)wg*64*E_ + idx];
            __syncthreads();
            int r = tid >> 2, q = tid & 3;
            float au = 0.f, ad = 0.f;
            #pragma unroll 4
            for (int k = 0; k < E_; ++k) {
                float m = Mt[r][k];
                au += m*uw[k*NE + q];
                if (q < 2) ad += m*dw[k*2 + q];
            }
            int row = wg*64 + r;
            ump[row*NE + q] = au;
            if (q < 2) dmp[row*2 + q] = ad;
        } else if (b < 480) {              // uip/dip from inv/pa
            int wg = b - 448;
            __shared__ float At3[64][E_];
            for (int idx = tid; idx < 64*E_; idx += 256) {
                int r = idx >> 7, k = idx & 127;
                int row = wg*64 + r;
                At3[r][k] = (k < 64) ? inv_all[row*RH + k] : pa_all[row*LE + (k - 64)];
            }
            __syncthreads();
            int r = tid >> 2, q = tid & 3;
            float au = ub[q], ad = (q < 2) ? db[q] : 0.f;
            #pragma unroll 4
            for (int k = 0; k < E_; ++k) {
                float v = At3[r][k];
                au += v*uw[(192 + k)*NE + q];
                if (q < 2) ad += v*dw[(192 + k)*2 + q];
            }
            int row = wg*64 + r;
            uip[row*NE + q] = au;
            if (q < 2) dip[row*2 + q] = ad;
        } else {                           // legacy
            if (tid < 64) {
                p_arr[tid] = p0[tid];
                pflag[tid] = 1;
            }
        }
    } else if (b < 2785) {
        // ---------------- kern_all MFMA (identical arithmetic) ----------------
        int bb = b - 481;
        int cb = bb % 72, rb = bb / 72;
        int lane = tid & 63, wv = tid >> 6;
        int quad = lane >> 4, xl = lane & 15;

        __shared__ _Float16 Ah[128*40], Al[128*40];
        __shared__ _Float16 Bh[128*40], Bl[128*40];

        floatx4 a0[2][8], a1[2][8];
        #pragma unroll
        for (int rt = 0; rt < 2; ++rt)
            #pragma unroll
            for (int ct = 0; ct < 8; ++ct) {
                a0[rt][ct] = (floatx4){0.f,0.f,0.f,0.f};
                a1[rt][ct] = (floatx4){0.f,0.f,0.f,0.f};
            }

        for (int kc = 0; kc < 4; ++kc) {
            #pragma unroll
            for (int l = 0; l < 4; ++l) {          // A chunk: 128 rows x 32 k
                int idx = tid + l*256;
                int r = idx >> 3, kq = idx & 7;
                float4 v = *(const float4*)&M[(size_t)(rb*128 + r)*E_ + kc*32 + kq*4];
                half4 hv, lv;
                hv.x=(_Float16)v.x; lv.x=(_Float16)((v.x-(float)hv.x)*1024.f);
                hv.y=(_Float16)v.y; lv.y=(_Float16)((v.y-(float)hv.y)*1024.f);
                hv.z=(_Float16)v.z; lv.z=(_Float16)((v.z-(float)hv.z)*1024.f);
                hv.w=(_Float16)v.w; lv.w=(_Float16)((v.w-(float)hv.w)*1024.f);
                *(half4*)&Ah[r*40 + kq*4] = hv;
                *(half4*)&Al[r*40 + kq*4] = lv;
            }
            #pragma unroll
            for (int l = 0; l < 4; ++l) {          // B chunk: 128 cols x 32 k
                int idx = tid + l*256;
                int c = idx >> 3, kq = idx & 7;
                float4 v = *(const float4*)&kernel_wpT[(size_t)(cb*128 + c)*E_ + kc*32 + kq*4];
                half4 hv, lv;
                hv.x=(_Float16)v.x; lv.x=(_Float16)((v.x-(float)hv.x)*1024.f);
                hv.y=(_Float16)v.y; lv.y=(_Float16)((v.y-(float)hv.y)*1024.f);
                hv.z=(_Float16)v.z; lv.z=(_Float16)((v.z-(float)hv.z)*1024.f);
                hv.w=(_Float16)v.w; lv.w=(_Float16)((v.w-(float)hv.w)*1024.f);
                *(half4*)&Bh[c*40 + kq*4] = hv;
                *(half4*)&Bl[c*40 + kq*4] = lv;
            }
            __syncthreads();
            half8 ah[2], al[2];
            #pragma unroll
            for (int rt = 0; rt < 2; ++rt) {
                int m = wv*32 + rt*16 + xl;
                ah[rt] = *(const half8*)&Ah[m*40 + quad*8];
                al[rt] = *(const half8*)&Al[m*40 + quad*8];
            }
            #pragma unroll
            for (int ct = 0; ct < 8; ++ct) {
                int c = ct*16 + xl;
                half8 bh = *(const half8*)&Bh[c*40 + quad*8];
                half8 bl = *(const half8*)&Bl[c*40 + quad*8];
                #pragma unroll
                for (int rt = 0; rt < 2; ++rt) {
                    a0[rt][ct] = __builtin_amdgcn_mfma_f32_16x16x32_f16(ah[rt], bh, a0[rt][ct], 0,0,0);
                    a1[rt][ct] = __builtin_amdgcn_mfma_f32_16x16x32_f16(al[rt], bh, a1[rt][ct], 0,0,0);
                    a1[rt][ct] = __builtin_amdgcn_mfma_f32_16x16x32_f16(ah[rt], bl, a1[rt][ct], 0,0,0);
                }
            }
            __syncthreads();
        }
        #pragma unroll
        for (int ct = 0; ct < 8; ++ct) {
            int colp = cb*128 + ct*16 + xl;
            int c = colp / 144, rr = colp % 144;
            int ta = rr >> 4, d = rr & 15;
            float kb = kernel_b[c*144 + d*9 + ta];
            #pragma unroll
            for (int rt = 0; rt < 2; ++rt)
                #pragma unroll
                for (int r = 0; r < 4; ++r) {
                    float v = a0[rt][ct][r] + a1[rt][ct][r]*(1.f/1024.f) + kb;
                    _Float16 h = (_Float16)v;
                    _Float16 lo = (_Float16)((v - (float)h)*1024.f);
                    union { _Float16 f; unsigned short u; } H, L;
                    H.f = h; L.f = lo;
                    size_t row = (size_t)rb*128 + wv*32 + rt*16 + quad*4 + r;
                    kernu[row*(size_t)KCOLS + colp] = ((unsigned)L.u << 16) | (unsigned)H.u;
                }
        }
    } else {
        // ---------------- giM (256-thread variant, identical per-g arithmetic) ------
        int ob = b - 2785;                 // 0..1023
        int lblk = ob & 7, n = (ob >> 3) & 63, dir = ob >> 9;
        __shared__ float Ml[8][E_];
        for (int idx = tid; idx < 8*E_; idx += 256) {
            int r = idx >> 7, k = idx & 127;
            Ml[r][k] = M[(n*NL + lblk*8 + r)*E_ + k];
        }
        __syncthreads();
        const float4* W = (const float4*)(wiT4) + dir*32*384;
        for (int g = tid; g < 384; g += 256) {
            float acc[8];
            #pragma unroll
            for (int r = 0; r < 8; ++r) acc[r] = 0.f;
            for (int kq = 0; kq < 32; ++kq) {
                float4 w = W[kq*384 + g];
                #pragma unroll
                for (int r = 0; r < 8; ++r) {
                    float4 h = *(const float4*)&Ml[r][kq*4];
                    acc[r] += w.x*h.x + w.y*h.y + w.z*h.z + w.w*h.w;
                }
            }
            float bi = dir ? bib[g] : bif[g];
            #pragma unroll
            for (int r = 0; r < 8; ++r)
                giM[((dir*N_ + n)*NL + lblk*8 + r)*G3 + g] = acc[r] + bi;
        }
    }
}

// ---------------- MFMA GRU with LDS ring-buffer for giM rows ------------------------
__global__ __launch_bounds__(256, 2) void k_gru(const float* giM, const _Float16* WBpack,
                                                const float* bhf, const float* bhb,
                                                const float* beta_w, const float* beta_b,
                                                float* Ball) {
    int b = blockIdx.x;
    int x = b & 7, m = b >> 3;
    int pblk = m & 3;
    int s = x + 8*(m >> 2);
    int dir = s >> 6, n = s & 63;
    int tid = threadIdx.x;
    int w = tid >> 6;
    int lane = tid & 63;
    int quad = lane >> 4;
    int col  = lane & 15;

    __shared__ _Float16 Hhi[16*136];
    __shared__ _Float16 Hlo[16*136];
    __shared__ float    Hf[16*132];
    __shared__ float    bwT[4*132];
    __shared__ float    giR[32][G3];      // 48KB ring of giM rows
    for (int idx = tid; idx < 16*136; idx += 256) { Hhi[idx] = (_Float16)0.f; Hlo[idx] = (_Float16)0.f; }
    for (int idx = tid; idx < 16*132; idx += 256) Hf[idx] = 0.f;
    for (int idx = tid; idx < 512; idx += 256) { int k = idx >> 2, e = idx & 3; bwT[e*132 + k] = beta_w[k*NE + e]; }

    half8 WB[48];
    const half8* wsrc = (const half8*)(WBpack) + ((size_t)(dir*4 + w)*4)*12*64;
    #pragma unroll
    for (int f = 0; f < 48; ++f) WB[f] = wsrc[(size_t)f*64 + lane];

    const float* bh = dir ? bhb : bhf;
    float bhv[6];
    #pragma unroll
    for (int gt2 = 0; gt2 < 3; ++gt2) {
        bhv[gt2*2+0] = bh[gt2*128 + w*32 + col];
        bhv[gt2*2+1] = bh[gt2*128 + w*32 + col + 16];
    }
    const float* giBase = giM + (size_t)(dir*N_ + n)*NL*G3;

    // preload window for j=0
    {
        int start0 = dir ? ((pblk*16 + 63) & 63) : (pblk*16 & 63);
        for (int idx = tid; idx < 16*G3; idx += 256) {
            int sr = idx / G3, e = idx - sr*G3;
            int l = (start0 + sr) & 63;
            giR[l & 31][e] = giBase[(size_t)l*G3 + e];
        }
    }

    int bseq = tid >> 4, bsub = tid & 15, bee = bsub & 3, bpart = bsub >> 2;
    float bbias = beta_b[bee];
    __syncthreads();

    for (int j = 0; j < NL; ++j) {
        floatx4 C[6];
        #pragma unroll
        for (int reg = 0; reg < 4; ++reg) {
            int seq = quad*4 + reg;
            int p = pblk*16 + seq;
            int l = dir ? ((p + 63 - j) & 63) : ((p + j) & 63);
            const float* gl = &giR[l & 31][w*32 + col];
            #pragma unroll
            for (int gt2 = 0; gt2 < 2; ++gt2)
                #pragma unroll
                for (int isub = 0; isub < 2; ++isub)
                    C[gt2*2 + isub][reg] = gl[gt2*128 + isub*16] + bhv[gt2*2+isub];
            #pragma unroll
            for (int isub = 0; isub < 2; ++isub)
                C[4 + isub][reg] = bhv[4+isub];
        }
        #pragma unroll
        for (int kt = 0; kt < 4; ++kt) {
            int off = col*136 + kt*32 + quad*8;
            half8 ahi = *(const half8*)&Hhi[off];
            half8 alo = *(const half8*)&Hlo[off];
            #pragma unroll
            for (int nt = 0; nt < 6; ++nt) {
                half8 bhi2 = WB[kt*12 + nt];
                half8 blo2 = WB[kt*12 + 6 + nt];
                C[nt] = __builtin_amdgcn_mfma_f32_16x16x32_f16(ahi, bhi2, C[nt], 0,0,0);
                C[nt] = __builtin_amdgcn_mfma_f32_16x16x32_f16(alo, bhi2, C[nt], 0,0,0);
                C[nt] = __builtin_amdgcn_mfma_f32_16x16x32_f16(ahi, blo2, C[nt], 0,0,0);
            }
        }
        __syncthreads();

        if (j < 63) {
            int lnext = dir ? ((pblk*16 + 62 - j) & 63) : ((pblk*16 + j + 16) & 63);
            for (int idx = tid; idx < G3; idx += 256)
                giR[lnext & 31][idx] = giBase[(size_t)lnext*G3 + idx];
        }

        #pragma unroll
        for (int reg = 0; reg < 4; ++reg) {
            int seq = quad*4 + reg;
            int p = pblk*16 + seq;
            int l = dir ? ((p + 63 - j) & 63) : ((p + j) & 63);
            const float* gl2 = &giR[l & 31][256 + w*32 + col];
            #pragma unroll
            for (int isub = 0; isub < 2; ++isub) {
                int i = w*32 + isub*16 + col;
                float r  = fsig(C[isub][reg]);
                float z  = fsig(C[2 + isub][reg]);
                float nn = ftanh(gl2[isub*16] + r*C[4 + isub][reg]);
                float hold = Hf[seq*132 + i];
                float hnew = (1.f - z)*nn + z*hold;
                _Float16 hi = (_Float16)hnew;
                _Float16 lo = (_Float16)(hnew - (float)hi);
                Hf[seq*132 + i] = hnew;
                Hhi[seq*136 + i] = hi;
                Hlo[seq*136 + i] = lo;
            }
        }
        __syncthreads();

        {
            float acc = 0.f;
            const float* hrow = &Hf[bseq*132];
            const float* brow = &bwT[bee*132];
            #pragma unroll 8
            for (int kk = 0; kk < 32; ++kk) {
                int k2 = bpart + 4*kk;
                acc += hrow[k2]*brow[k2];
            }
            acc += __shfl_xor(acc, 4);
            acc += __shfl_xor(acc, 8);
            if (bpart == 0) {
                float bval = fsig(acc + bbias);
                int p = pblk*16 + bseq;
                Ball[((n*NL + p)*128 + 2*j + dir)*NE + bee] = bval;
            }
        }
    }
}

// ---------------- self-contained T-loop: 9 waves, tail partA on waves 4-7 -----------
// phase C: waves 0-3 MFMA conv | waves 4-7 tail partA(t-1) (z1/pla/pc quarters) |
//          wave 8 stager. B1.
// seg2: waves 0-3 redundant decision (spine) | wave 4 tail partB(t-1). B2.
__global__ __launch_bounds__(576, 1) void k_step(
    const float* obs, const unsigned int* kernu, const float* conv_bias,
    const float* zmp, const float* zip,
    const float* ump, const float* uip, const float* dmp, const float* dip,
    const float* zw, const float* aw, const float* ab,
    const float* uw, const float* dw, const float* cw, const float* cb,
    const float* amask, const float* Ball, const int* p0,
    float* out) {

    int n = blockIdx.x, tid = threadIdx.x;

    __shared__ __align__(16) _Float16 obs_h[2][OPL];     // padded [19][18+pad][OXP] hi
    __shared__ __align__(16) _Float16 obs_lo[2][OPL];    // lo * 1024
    __shared__ __align__(16) _Float16 klh[64*KPITCH];    // kern hi, [c][k' padded]
    __shared__ __align__(16) _Float16 kll[64*KPITCH];    // kern lo * 1024
    __shared__ float h1part[4][64];
    __shared__ __align__(16) float zml[2][HD];
    __shared__ __align__(16) float zil[2][HD];
    __shared__ __align__(16) float Pl[HD];
    __shared__ __align__(16) float Btmp[HD];             // Ball row scratch (stager)
    __shared__ __align__(16) float aml[2][16];
    __shared__ __align__(16) float uws[CH*NE];
    __shared__ __align__(16) float dws[CH*2];
    __shared__ float cbl[CH];
    __shared__ __align__(16) float umpl[4];
    __shared__ __align__(16) float uipl[4];
    __shared__ __align__(8)  float dmpl[2];
    __shared__ __align__(8)  float dipl[2];
    __shared__ float h1l[2][CH];
    __shared__ __align__(16) float z1l[HD];
    __shared__ float pla[128];
    __shared__ float pc[32];
    __shared__ float la[A_];
    __shared__ float lu[4];
    __shared__ float ld2[2];
    __shared__ float scv[1];
    __shared__ int   psint[2];

    int lane = tid & 63;
    int wv   = tid >> 6;
    int quad = lane >> 4;
    int xl   = lane & 15;

    // ---- kern row (interleaved uint) -> LDS hi/lo split (waves 0-3) ----
    auto stage_kern = [&](int prow) {
        if (tid < 256) {
            const uint4* src = (const uint4*)(kernu + (size_t)(n*NL + prow)*KCOLS);
            #pragma unroll
            for (int l = 0; l < 9; ++l) {
                int i = tid + l*256;            // 2304 uint4
                uint4 v = src[i];
                int e = i*4;
                int c = e / 144, k = e - c*144; // k 4-aligned within channel
                union { unsigned short u[4]; half4 h; } H, L;
                H.u[0] = (unsigned short)(v.x & 0xffffu); L.u[0] = (unsigned short)(v.x >> 16);
                H.u[1] = (unsigned short)(v.y & 0xffffu); L.u[1] = (unsigned short)(v.y >> 16);
                H.u[2] = (unsigned short)(v.z & 0xffffu); L.u[2] = (unsigned short)(v.z >> 16);
                H.u[3] = (unsigned short)(v.w & 0xffffu); L.u[3] = (unsigned short)(v.w >> 16);
                *(half4*)&klh[c*KPITCH + k] = H.h;
                *(half4*)&kll[c*KPITCH + k] = L.h;
            }
        }
    };

    // ---- tail partA (waves 4-7): z1/pla/pc quarters; identical per-entry arithmetic
    auto tail_partA = [&](int tt, int bpar) {
        int w47 = (tid - 256) >> 6;       // 0..3 (waves 4-7)
        int ln  = tid & 63;
        size_t ob2 = ((size_t)tt*N_ + n)*OUTW;
        // z1 quarter: c8 in {w47*2, w47*2+1}
        #pragma unroll
        for (int c8i = 0; c8i < 2; ++c8i) {
            int c8 = w47*2 + c8i;
            int h = c8*64 + ln;
            float a2 = zml[bpar][h] + zil[bpar][h];
            #pragma unroll 16
            for (int cc = 0; cc < CH; ++cc) a2 += h1l[bpar][cc]*zw[(E_ + cc)*HD + h];
            float v = fmaxf(a2, 0.f);
            z1l[h] = v;
            out[ob2 + 146 + h] = v;
        }
        // pla partials: 2 parts per wave (own z1 quarter); lanes 0..31
        if (ln < 32) {
            int a3 = ln & 15, part = w47*2 + (ln >> 4);
            float acc2 = 0.f;
            const float* z0 = z1l + part*64;
            #pragma unroll 16
            for (int h = 0; h < 64; ++h) acc2 += z0[h]*aw[(part*64 + h)*A_ + a3];
            pla[a3*8 + part] = acc2;
        } else if (ln < 40) {
            // pc partials: 8 entries per wave (own z1 quarter)
            int e = w47*8 + (ln - 32);
            float acc2 = 0.f;
            const float* z0 = z1l + e*16;
            #pragma unroll 16
            for (int h = 0; h < 16; ++h) acc2 += z0[h]*cw[e*16 + h];
            pc[e] = acc2;
        }
    };

    // ---- tail partB (wave 4, after a barrier): la/sc/softmax/out ----
    auto tail_partB = [&](int tt, int bpar) {
        int ln = tid - 256;               // 0..63 (wave 4)
        size_t ob2 = ((size_t)tt*N_ + n)*OUTW;
        if (ln < A_) {
            float acc2 = ab[ln];
            #pragma unroll
            for (int k = 0; k < 8; ++k) acc2 += pla[ln*8 + k];
            la[ln] = acc2;
        } else if (ln == 24) {
            float acc2 = cb[0];
            #pragma unroll
            for (int k = 0; k < 32; ++k) acc2 += pc[k];
            scv[0] = acc2;
        }
        if (ln == 0) {
            float mx = la[0];
            #pragma unroll
            for (int k2 = 1; k2 < A_; ++k2) mx = fmaxf(mx, la[k2]);
            float pr[A_]; float sum = 0.f;
            #pragma unroll
            for (int k2 = 0; k2 < A_; ++k2) { pr[k2] = expf(la[k2]-mx); sum += pr[k2]; }
            const float* am = &aml[bpar][0];
            float best = -1.f; int bi2 = 0;
            #pragma unroll
            for (int k2 = 0; k2 < A_; ++k2) {
                float v = pr[k2]/sum * am[k2];
                out[ob2 + 1 + k2] = v;
                if (v > best) { best = v; bi2 = k2; }
            }
            out[ob2 + 0] = (float)bi2;
        } else if (ln == 1) {
            out[ob2 + 659] = scv[0];
        }
    };

    // ---------------- prologue ----------------
    int pcur = p0[n];
    {
        if (tid == 0) psint[1] = pcur;
        for (int i = tid; i < OPL; i += 576) {
            obs_h[0][i] = (_Float16)0.f; obs_h[1][i] = (_Float16)0.f;
            obs_lo[0][i] = (_Float16)0.f; obs_lo[1][i] = (_Float16)0.f;
        }
        for (int i = tid; i < 64*(KPITCH-144); i += 576) {
            int c = i / (KPITCH-144), k = 144 + i % (KPITCH-144);
            klh[c*KPITCH + k] = (_Float16)0.f;
            kll[c*KPITCH + k] = (_Float16)0.f;
        }
        if (tid < 64) cbl[tid] = conv_bias[tid];
        if (tid < 256) {
            uws[tid] = uw[(E_ + (tid >> 2))*NE + (tid & 3)];
            if (tid < 128) dws[tid] = dw[(E_ + (tid >> 1))*2 + (tid & 1)];
        }
    }
    __syncthreads();
    {
        if (tid < 256) {
            const float4* op4 = (const float4*)(obs + (size_t)(0*N_ + n)*D_*HW*HW);
            #pragma unroll
            for (int k4 = 0; k4 < 4; ++k4) {
                int idx = tid + k4*256;
                float4 v = op4[idx];
                int d = idx >> 6, rem = idx & 63;
                int y = rem >> 2, xq = rem & 3;
                int base = (y+1)*OROW + (xq*4+1)*OXP + d;
                _Float16 h0=(_Float16)v.x, h1=(_Float16)v.y, h2=(_Float16)v.z, h3=(_Float16)v.w;
                obs_h[0][base+0*OXP] = h0; obs_lo[0][base+0*OXP] = (_Float16)((v.x-(float)h0)*1024.f);
                obs_h[0][base+1*OXP] = h1; obs_lo[0][base+1*OXP] = (_Float16)((v.y-(float)h1)*1024.f);
                obs_h[0][base+2*OXP] = h2; obs_lo[0][base+2*OXP] = (_Float16)((v.z-(float)h2)*1024.f);
                obs_h[0][base+3*OXP] = h3; obs_lo[0][base+3*OXP] = (_Float16)((v.w-(float)h3)*1024.f);
            }
        }
        stage_kern(pcur);
    }
    __syncthreads();

    for (int t = 0; t < T_; ++t) {
        int par = t & 1;
        size_t ob = ((size_t)t*N_ + n)*OUTW;

        // ==== phase C: conv (w0-3) | tail partA(t-1) (w4-7) | stager (w8) ==========
        if (tid < 256) {
            floatx4 a0[4][4];
            floatx4 a1[4][4];
            #pragma unroll
            for (int jm = 0; jm < 4; ++jm)
                #pragma unroll
                for (int ct = 0; ct < 4; ++ct) {
                    a0[jm][ct] = (floatx4){0.f,0.f,0.f,0.f};
                    a1[jm][ct] = (floatx4){0.f,0.f,0.f,0.f};
                }
            const _Float16* Oh = &obs_h[par][0];
            const _Float16* Ol = &obs_lo[par][0];
            #pragma unroll
            for (int kt = 0; kt < 5; ++kt) {
                int pi = kt*2 + (quad >> 1);
                int ky = (pi*11) >> 5;          // floor(pi/3), pi in 0..9
                int kx = pi - ky*3;
                int aoff = ky*OROW + kx*OXP + ((quad & 1) << 3) + xl*OXP;
                half8 ah[4], al[4];
                #pragma unroll
                for (int jm = 0; jm < 4; ++jm) {
                    int y = wv*4 + jm;
                    int o = aoff + y*OROW;
                    ah[jm] = *(const half8*)&Oh[o];
                    al[jm] = *(const half8*)&Ol[o];
                }
                #pragma unroll
                for (int ct = 0; ct < 4; ++ct) {
                    int bo = (ct*16 + xl)*KPITCH + kt*32 + quad*8;
                    half8 bh = *(const half8*)&klh[bo];
                    half8 bl = *(const half8*)&kll[bo];
                    #pragma unroll
                    for (int jm = 0; jm < 4; ++jm) {
                        a0[jm][ct] = __builtin_amdgcn_mfma_f32_16x16x32_f16(ah[jm], bh, a0[jm][ct], 0,0,0);
                        a1[jm][ct] = __builtin_amdgcn_mfma_f32_16x16x32_f16(al[jm], bh, a1[jm][ct], 0,0,0);
                        a1[jm][ct] = __builtin_amdgcn_mfma_f32_16x16x32_f16(ah[jm], bl, a1[jm][ct], 0,0,0);
                    }
                }
            }
            #pragma unroll
            for (int ct = 0; ct < 4; ++ct) {
                float bc = cbl[ct*16 + xl];
                float s = 0.f;
                #pragma unroll
                for (int jm = 0; jm < 4; ++jm) {
                    float sj = 0.f;
                    #pragma unroll
                    for (int r = 0; r < 4; ++r)
                        sj += fmaxf(a0[jm][ct][r] + a1[jm][ct][r]*(1.f/1024.f) + bc, 0.f);
                    s += sj;
                }
                s += __shfl_xor(s, 16);
                s += __shfl_xor(s, 32);
                if (quad == 0) h1part[wv][ct*16 + xl] = s;
            }
        } else if (tid < 512) {
            if (t > 0) tail_partA(t - 1, 1 - par);
        } else {
            // wave 8: stager; p(t) from psint (written pre-B2 of step t-1)
            int ln5 = tid - 512;
            int pp = psint[1];
            const float4* Brow = (const float4*)(Ball + (size_t)(n*NL + pp)*128*NE);
            const float4* Zm   = (const float4*)(zmp  + (size_t)(n*NL + pp)*HD);
            const float4* Zi   = (const float4*)(zip  + (size_t)(t*N_ + n)*HD);
            #pragma unroll
            for (int k = 0; k < 2; ++k) {
                ((float4*)Btmp)[k*64 + ln5]         = Brow[k*64 + ln5];
                ((float4*)&zml[par][0])[k*64 + ln5] = Zm[k*64 + ln5];
                ((float4*)&zil[par][0])[k*64 + ln5] = Zi[k*64 + ln5];
            }
            if (ln5 < 4) {
                ((float4*)&aml[par][0])[ln5] = ((const float4*)(amask + ((size_t)t*N_ + n)*A_))[ln5];
            } else if (ln5 == 4) {
                *(float4*)umpl = *(const float4*)(ump + (size_t)(n*NL + pp)*NE);
            } else if (ln5 == 5) {
                *(float4*)uipl = *(const float4*)(uip + (size_t)(t*N_ + n)*NE);
            } else if (ln5 == 6) {
                *(float2*)dmpl = *(const float2*)(dmp + (size_t)(n*NL + pp)*2);
            } else if (ln5 == 7) {
                *(float2*)dipl = *(const float2*)(dip + (size_t)(t*N_ + n)*2);
            }
            // stick-breaking -> reordered Pl (bit-identical to old k_P)
            if (ln5 < NE) {
                int e = ln5;
                float c = 1.f;
                for (int j2 = 0; j2 < 128; ++j2) {
                    float bzv = (j2 == 0 || j2 == 127) ? 0.f : Btmp[j2*NE + e];
                    float bf = (j2 == 127) ? 1.f : bzv;
                    float pf = bf * c;
                    c *= (1.f - bzv);
                    int j = (j2 & 1) ? (63 - ((j2 - 1) >> 1)) : ((j2 >> 1) + 64);
                    Pl[j*NE + e] = pf;
                }
            }
            if (t + 1 < T_) {
                const float4* op4 = (const float4*)(obs + (size_t)((t+1)*N_ + n)*D_*HW*HW);
                _Float16* dh = &obs_h[1 - par][0];
                _Float16* dl = &obs_lo[1 - par][0];
                #pragma unroll
                for (int k4 = 0; k4 < 16; ++k4) {
                    int idx = k4*64 + ln5;
                    float4 v = op4[idx];
                    int d = idx >> 6, rem = idx & 63;
                    int y = rem >> 2, xq = rem & 3;
                    int base = (y+1)*OROW + (xq*4+1)*OXP + d;
                    _Float16 h0=(_Float16)v.x, h1=(_Float16)v.y, h2=(_Float16)v.z, h3=(_Float16)v.w;
                    dh[base+0*OXP] = h0; dl[base+0*OXP] = (_Float16)((v.x-(float)h0)*1024.f);
                    dh[base+1*OXP] = h1; dl[base+1*OXP] = (_Float16)((v.y-(float)h1)*1024.f);
                    dh[base+2*OXP] = h2; dl[base+2*OXP] = (_Float16)((v.z-(float)h2)*1024.f);
                    dh[base+3*OXP] = h3; dl[base+3*OXP] = (_Float16)((v.w-(float)h3)*1024.f);
                }
            }
        }
        __syncthreads();   // B1

        // ========= seg2: decision (w0-3, spine) | tail partB(t-1) (w4) ============
        if (wv < 4) {
            float hp = ((h1part[0][lane] + h1part[1][lane]) + h1part[2][lane]) + h1part[3][lane];
            h1l[par][lane] = hp;
            if (lane < 4) {
                float a2 = umpl[lane] + uipl[lane];
                #pragma unroll 16
                for (int cc = 0; cc < CH; ++cc) a2 += h1l[par][cc]*uws[cc*4 + lane];
                lu[lane] = a2;
            } else if (lane < 6) {
                int g = lane - 4;
                float a2 = dmpl[g] + dipl[g];
                #pragma unroll 16
                for (int cc = 0; cc < CH; ++cc) a2 += h1l[par][cc]*dws[cc*2 + g];
                ld2[g] = a2;
            }
            float l0 = lu[0], l1 = lu[1], l2 = lu[2], l3 = lu[3];
            float d0 = ld2[0], d1 = ld2[1];
            float mx = fmaxf(fmaxf(l0, l1), fmaxf(l2, l3));
            float e0u = expf(l0-mx), e1u = expf(l1-mx), e2u = expf(l2-mx), e3u = expf(l3-mx);
            float su = ((e0u + e1u) + e2u) + e3u;
            float uv0 = e0u/su, uv1 = e1u/su, uv2 = e2u/su, uv3 = e3u/su;
            int dg = (d1 > d0) ? 1 : 0;

            float4 Pva = ((const float4*)Pl)[lane];
            float4 Pvb = ((const float4*)Pl)[lane + 64];
            float va = Pva.x*uv0 + Pva.y*uv1 + Pva.z*uv2 + Pva.w*uv3;
            float vb = Pvb.x*uv0 + Pvb.y*uv1 + Pvb.z*uv2 + Pvb.w*uv3;
            if (tid < 64) {
                out[ob + 18 + lane] = va;
                out[ob + 82 + lane] = vb;
            }
            float bv = va; int bj = lane;
            if (vb > va) { bv = vb; bj = lane + 64; }
            #pragma unroll
            for (int off2 = 1; off2 < 64; off2 <<= 1) {
                float v2 = __shfl_xor(bv, off2);
                int   j2 = __shfl_xor(bj, off2);
                if (v2 > bv || (v2 == bv && j2 < bj)) { bv = v2; bj = j2; }
            }
            int dsel = dg ? bj : 64;
            int pn = pcur + dsel - 64;
            pn = pn < 0 ? 0 : (pn > 63 ? 63 : pn);
            if (tid == 0) {
                out[ob + 17]  = (float)dsel;
                out[ob + 658] = (float)pn;
                psint[1] = pn;             // publish for the stager wave
            } else if (tid == 2) {
                float mx2 = fmaxf(d0, d1);
                float q0 = expf(d0-mx2), q1 = expf(d1-mx2);
                float s2 = q0 + q1;
                out[ob + 660] = q0/s2;
                out[ob + 661] = q1/s2;
                out[ob + 662] = (float)dg;
            }
            if (t + 1 < T_ && pn != pcur) stage_kern(pn);
            pcur = pn;
        } else if (wv == 4) {
            if (t > 0) tail_partB(t - 1, 1 - par);
        }
        __syncthreads();   // B2 (end of step)
    }

    // final tail for t = T-1 (parity 1): partA on waves 4-7, barrier, partB on wave 4
    if (tid >= 256 && tid < 512) tail_partA(T_ - 1, 1);
    __syncthreads();
    if (wv == 4) tail_partB(T_ - 1, 1);
}

extern "C" void kernel_launch(void* const* d_in, const int* in_sizes, int n_in,
                              void* d_out, int out_size, void* d_ws, size_t ws_size,
                              hipStream_t stream) {
    (void)in_sizes; (void)n_in; (void)out_size; (void)ws_size;
    const int*   lines    = (const int*)  d_in[0];
    const float* obs      = (const float*)d_in[1];
    const float* invent   = (const float*)d_in[2];
    const int*   pa       = (const int*)  d_in[3];
    const float* amask    = (const float*)d_in[4];
    const int*   p0       = (const int*)  d_in[5];
    const float* emb_task = (const float*)d_in[6];
    const float* emb_low  = (const float*)d_in[7];
    const float* wi_f     = (const float*)d_in[8];
    const float* wh_f     = (const float*)d_in[9];
    const float* bi_f     = (const float*)d_in[10];
    const float* bh_f     = (const float*)d_in[11];
    const float* wi_b     = (const float*)d_in[12];
    const float* wh_b     = (const float*)d_in[13];
    const float* bi_b     = (const float*)d_in[14];
    const float* bh_b     = (const float*)d_in[15];
    const float* beta_w   = (const float*)d_in[16];
    const float* beta_b   = (const float*)d_in[17];
    const float* kernel_w = (const float*)d_in[18];
    const float* kernel_b = (const float*)d_in[19];
    const float* conv_b   = (const float*)d_in[20];
    const float* inv_w    = (const float*)d_in[21];
    const float* inv_b    = (const float*)d_in[22];
    const float* zw       = (const float*)d_in[23];
    const float* zb       = (const float*)d_in[24];
    const float* aw       = (const float*)d_in[25];
    const float* ab       = (const float*)d_in[26];
    const float* uw       = (const float*)d_in[27];
    const float* ub       = (const float*)d_in[28];
    const float* dw       = (const float*)d_in[29];
    const float* db       = (const float*)d_in[30];
    const float* cw       = (const float*)d_in[31];
    const float* cb       = (const float*)d_in[32];
    float* out = (float*)d_out;

    float* ws = (float*)d_ws;
    size_t off = 0;
    float* M        = ws + off; off += (size_t)N_*NL*E_;
    float* wiT4     = ws + off; off += 2*32*384*4;
    _Float16* WBpack = (_Float16*)(ws + off); off += (size_t)384*512/2;
    float* giM      = ws + off; off += (size_t)2*N_*NL*G3;
    float* Ball     = ws + off; off += (size_t)N_*NL*128*NE;
    float* Pall     = ws + off; off += (size_t)N_*NL*128*NE;   // unused (layout stability)
    float* inv_all  = ws + off; off += (size_t)T_*N_*RH;
    float* pa_all   = ws + off; off += (size_t)T_*N_*LE;
    unsigned int* kernu = (unsigned int*)(ws + off); off += (size_t)N_*NL*KCOLS; // 151 MB interleaved hi/lo
    float* h1_buf   = ws + off; off += (size_t)T_*N_*64;      // legacy, unused
    float* zmp      = ws + off; off += (size_t)N_*NL*HD;
    float* zip      = ws + off; off += (size_t)T_*N_*HD;
    float* ump      = ws + off; off += (size_t)N_*NL*NE;
    float* dmp      = ws + off; off += (size_t)N_*NL*2;
    float* uip      = ws + off; off += (size_t)T_*N_*NE;
    float* dip      = ws + off; off += (size_t)T_*N_*2;
    int*   flags    = (int*)(ws + off); off += 36992;
    int*   pflag    = flags + 32768;
    int*   p_arr    = pflag + 2112;
    float* kernel_wpT = ws + off; off += (size_t)E_*KCOLS;    // 4.7 MB, [colp][k]
    (void)h1_buf; (void)Pall;

    k_prep1<<<2225, 256, 0, stream>>>(lines, emb_task, M, wi_f, wi_b, wiT4,
                                      wh_f, wh_b, WBpack,
                                      invent, inv_w, inv_b, pa, emb_low, inv_all, pa_all,
                                      flags, kernel_w, kernel_wpT);
    k_mid<<<3809, 256, 0, stream>>>(M, inv_all, pa_all, zw, zb, uw, ub, dw, db,
                                    p0, p_arr, pflag,
                                    zmp, zip, ump, dmp, uip, dip,
                                    kernel_wpT, kernel_b, kernu,
                                    wiT4, bi_f, bi_b, giM);
    k_gru<<<512, 256, 0, stream>>>(giM, WBpack, bh_f, bh_b, beta_w, beta_b, Ball);

    k_step<<<64, 576, 0, stream>>>(obs, kernu, conv_b,
                                   zmp, zip, ump, uip, dmp, dip,
                                   zw, aw, ab, uw, dw, cw, cb,
                                   amask, Ball, p0, out);
}

// Round 12
// 1138.070 us; speedup vs baseline: 1.3971x; 1.3971x over previous
//
#include <hip/hip_runtime.h>
#include <math.h>

#define T_   32
#define N_   64
#define NL   64
#define E_   128
#define G3   384   // 3*E
#define NE   4
#define CH   64
#define D_   16
#define HW   16
#define RH   64
#define LE   64
#define HD   512
#define A_   16
#define INVN 32
#define KCOLS 9216 // CH*D_*3*3
#define OUTW 663
#define OXP  24         // obs LDS x-pitch (halves)
#define OROW 456        // 18*OXP + 24 pad (y-stride 228 dw = 4 mod 32 -> 2-way)
#define OPL  8664       // 19 * OROW
#define KPITCH 168      // padded kern row pitch per channel (144 real + 24 pad)

typedef _Float16 half8 __attribute__((ext_vector_type(8)));
typedef _Float16 half4 __attribute__((ext_vector_type(4)));
typedef float floatx4 __attribute__((ext_vector_type(4)));

__device__ __forceinline__ float fsig(float x)  { return __builtin_amdgcn_rcpf(1.f + __expf(-x)); }
__device__ __forceinline__ float ftanh(float x) { return 1.f - 2.f*__builtin_amdgcn_rcpf(1.f + __expf(2.f*x)); }

// ---------------- merged prep 1: M, wiT4, WBpack, invpa, flags-zero, kernel_wT perm --
__global__ __launch_bounds__(256) void k_prep1(
    const int* lines, const float* emb_task, float* M,
    const float* wif, const float* wib, float* wiT4,
    const float* whf, const float* whb, _Float16* WBpack,
    const float* inv, const float* inv_w, const float* inv_b,
    const int* pa, const float* emb_lower, float* inv_all, float* pa_all,
    int* flags, const float* kernel_w, float* kernel_wpT) {
    int b = blockIdx.x, tid = threadIdx.x;
    __shared__ float Tt[128][149];     // transpose tile (only used by b>=2161)
    if (b < 1024) {                    // M: emb-bag sum
        #pragma unroll
        for (int r = 0; r < 2; ++r) {
            int idx = b*512 + r*256 + tid;
            int nl = idx >> 7, i = idx & 127;
            const int* ln = lines + nl*4;
            float s = 0.f;
            #pragma unroll
            for (int t = 0; t < 4; ++t) s += emb_task[ln[t]*E_ + i];
            M[nl*E_ + i] = s;
        }
    } else if (b < 1408) {             // wiT4 repack
        int ob = (b - 1024)*2 + (tid >> 7);
        int g = ob % 384, dir = ob / 384;
        int k = tid & 127;
        const float* wi = dir ? wib : wif;
        int dst = ((dir*32 + (k>>2))*384 + g)*4 + (k&3);
        wiT4[dst] = wi[g*128 + k];
    } else if (b < 1504) {             // WBpack fp16 hi/lo fragments
        int ob = (b - 1408)*4 + (tid >> 6);
        int lane = tid & 63;
        int nt = ob % 6; int rest = ob / 6;
        int term = rest % 2; rest /= 2;
        int kt = rest % 4; rest /= 4;
        int w = rest % 4; int dir = rest / 4;
        const float* wh = dir ? whb : whf;
        int gt = nt >> 1, isub = nt & 1;
        int g  = gt*128 + w*32 + isub*16 + (lane & 15);
        int k0 = kt*32 + (lane >> 4)*8;
        _Float16* dst = WBpack + (size_t)ob*512 + lane*8;
        #pragma unroll
        for (int e = 0; e < 8; ++e) {
            float v = wh[g*128 + k0 + e];
            _Float16 hi = (_Float16)v;
            dst[e] = (term == 0) ? hi : (_Float16)(v - (float)hi);
        }
    } else if (b < 2016) {             // inv relu + pa emb-bag
        int tn = (b - 1504)*4 + (tid >> 6);
        int r = tid & 63;
        const float* iv = inv + tn*INVN;
        float acc = inv_b[r];
        #pragma unroll
        for (int i = 0; i < INVN; ++i) acc += iv[i]*inv_w[i*RH + r];
        inv_all[tn*RH + r] = fmaxf(acc, 0.f);
        const int* pp = pa + tn*4;
        float s = 0.f;
        #pragma unroll
        for (int j = 0; j < 4; ++j) s += emb_lower[pp[j]*LE + r];
        pa_all[tn*LE + r] = s;
    } else if (b < 2161) {             // zero legacy flags
        int idx = (b - 2016)*256 + tid;
        if (idx < 36992) flags[idx] = 0;
    } else {                           // per-channel coalesced transpose (64 blocks)
        int c = b - 2161;              // 0..63
        for (int idx = tid; idx < 128*144; idx += 256) {
            int r = idx / 144, q = idx - r*144;
            Tt[r][q] = kernel_w[(size_t)r*KCOLS + c*144 + q];
        }
        __syncthreads();
        for (int idx = tid; idx < 144*128; idx += 256) {
            int cl = idx >> 7, k = idx & 127;   // cl = ta*16+d (permuted local col)
            int ta = cl >> 4, d = cl & 15;
            kernel_wpT[(size_t)(c*144 + cl)*E_ + k] = Tt[k][d*9 + ta];
        }
    }
}

// ---------------- fused mid kernel: prep2 | kern_all(MFMA) | giM -------------------
__global__ __launch_bounds__(256) void k_mid(
    const float* M, const float* inv_all, const float* pa_all,
    const float* zw, const float* zb,
    const float* uw, const float* ub, const float* dw, const float* db,
    const int* p0, int* p_arr, int* pflag,
    float* zmp, float* zip, float* ump, float* dmp, float* uip, float* dip,
    const float* kernel_wpT, const float* kernel_b, unsigned int* kernu,
    const float* wiT4, const float* bif, const float* bib, float* giM) {
    int b = blockIdx.x, tid = threadIdx.x;
    if (b < 481) {
        if (b < 256) {                     // zmp = M @ zw[0:128]
            int cb = b & 1, rb = b >> 1;
            __shared__ float At[32][E_];
            for (int idx = tid; idx < 32*E_; idx += 256) {
                int r = idx >> 7, k = idx & 127;
                At[r][k] = M[(rb*32 + r)*E_ + k];
            }
            __syncthreads();
            float acc[32];
            #pragma unroll
            for (int r = 0; r < 32; ++r) acc[r] = 0.f;
            int col = cb*256 + tid;
            #pragma unroll 4
            for (int k = 0; k < E_; ++k) {
                float w = zw[k*HD + col];
                #pragma unroll
                for (int r = 0; r < 32; ++r) acc[r] += At[r][k]*w;
            }
            #pragma unroll
            for (int r = 0; r < 32; ++r)
                zmp[(size_t)(rb*32 + r)*HD + col] = acc[r];
        } else if (b < 384) {              // zip = [inv|pa] @ zw[192:320] + zb
            int b2 = b - 256;
            int cb = b2 & 1, rb = b2 >> 1;
            __shared__ float At2[32][E_];
            for (int idx = tid; idx < 32*E_; idx += 256) {
                int r = idx >> 7, k = idx & 127;
                int row = rb*32 + r;
                At2[r][k] = (k < 64) ? inv_all[row*RH + k] : pa_all[row*LE + (k - 64)];
            }
            __syncthreads();
            float acc[32];
            #pragma unroll
            for (int r = 0; r < 32; ++r) acc[r] = 0.f;
            int col = cb*256 + tid;
            #pragma unroll 4
            for (int k = 0; k < E_; ++k) {
                float w = zw[(192 + k)*HD + col];
                #pragma unroll
                for (int r = 0; r < 32; ++r) acc[r] += At2[r][k]*w;
            }
            float bb = zb[col];
            #pragma unroll
            for (int r = 0; r < 32; ++r)
                zip[(size_t)(rb*32 + r)*HD + col] = acc[r] + bb;
        } else if (b < 448) {              // ump/dmp from M
            int wg = b - 384;
            __shared__ float Mt[64][E_];
            for (int idx = tid; idx < 64*E_; idx += 256)
                ((float*)Mt)[idx] = M[(size_t)wg*64*E_ + idx];
            __syncthreads();
            int r = tid >> 2, q = tid & 3;
            float au = 0.f, ad = 0.f;
            #pragma unroll 4
            for (int k = 0; k < E_; ++k) {
                float m = Mt[r][k];
                au += m*uw[k*NE + q];
                if (q < 2) ad += m*dw[k*2 + q];
            }
            int row = wg*64 + r;
            ump[row*NE + q] = au;
            if (q < 2) dmp[row*2 + q] = ad;
        } else if (b < 480) {              // uip/dip from inv/pa
            int wg = b - 448;
            __shared__ float At3[64][E_];
            for (int idx = tid; idx < 64*E_; idx += 256) {
                int r = idx >> 7, k = idx & 127;
                int row = wg*64 + r;
                At3[r][k] = (k < 64) ? inv_all[row*RH + k] : pa_all[row*LE + (k - 64)];
            }
            __syncthreads();
            int r = tid >> 2, q = tid & 3;
            float au = ub[q], ad = (q < 2) ? db[q] : 0.f;
            #pragma unroll 4
            for (int k = 0; k < E_; ++k) {
                float v = At3[r][k];
                au += v*uw[(192 + k)*NE + q];
                if (q < 2) ad += v*dw[(192 + k)*2 + q];
            }
            int row = wg*64 + r;
            uip[row*NE + q] = au;
            if (q < 2) dip[row*2 + q] = ad;
        } else {                           // legacy
            if (tid < 64) {
                p_arr[tid] = p0[tid];
                pflag[tid] = 1;
            }
        }
    } else if (b < 2785) {
        // ---------------- kern_all MFMA ----------------
        int bb = b - 481;
        int cb = bb % 72, rb = bb / 72;
        int lane = tid & 63, wv = tid >> 6;
        int quad = lane >> 4, xl = lane & 15;

        __shared__ _Float16 Ah[128*40], Al[128*40];
        __shared__ _Float16 Bh[128*40], Bl[128*40];

        floatx4 a0[2][8], a1[2][8];
        #pragma unroll
        for (int rt = 0; rt < 2; ++rt)
            #pragma unroll
            for (int ct = 0; ct < 8; ++ct) {
                a0[rt][ct] = (floatx4){0.f,0.f,0.f,0.f};
                a1[rt][ct] = (floatx4){0.f,0.f,0.f,0.f};
            }

        for (int kc = 0; kc < 4; ++kc) {
            #pragma unroll
            for (int l = 0; l < 4; ++l) {          // A chunk
                int idx = tid + l*256;
                int r = idx >> 3, kq = idx & 7;
                float4 v = *(const float4*)&M[(size_t)(rb*128 + r)*E_ + kc*32 + kq*4];
                half4 hv, lv;
                hv.x=(_Float16)v.x; lv.x=(_Float16)((v.x-(float)hv.x)*1024.f);
                hv.y=(_Float16)v.y; lv.y=(_Float16)((v.y-(float)hv.y)*1024.f);
                hv.z=(_Float16)v.z; lv.z=(_Float16)((v.z-(float)hv.z)*1024.f);
                hv.w=(_Float16)v.w; lv.w=(_Float16)((v.w-(float)hv.w)*1024.f);
                *(half4*)&Ah[r*40 + kq*4] = hv;
                *(half4*)&Al[r*40 + kq*4] = lv;
            }
            #pragma unroll
            for (int l = 0; l < 4; ++l) {          // B chunk
                int idx = tid + l*256;
                int c = idx >> 3, kq = idx & 7;
                float4 v = *(const float4*)&kernel_wpT[(size_t)(cb*128 + c)*E_ + kc*32 + kq*4];
                half4 hv, lv;
                hv.x=(_Float16)v.x; lv.x=(_Float16)((v.x-(float)hv.x)*1024.f);
                hv.y=(_Float16)v.y; lv.y=(_Float16)((v.y-(float)hv.y)*1024.f);
                hv.z=(_Float16)v.z; lv.z=(_Float16)((v.z-(float)hv.z)*1024.f);
                hv.w=(_Float16)v.w; lv.w=(_Float16)((v.w-(float)hv.w)*1024.f);
                *(half4*)&Bh[c*40 + kq*4] = hv;
                *(half4*)&Bl[c*40 + kq*4] = lv;
            }
            __syncthreads();
            half8 ah[2], al[2];
            #pragma unroll
            for (int rt = 0; rt < 2; ++rt) {
                int m = wv*32 + rt*16 + xl;
                ah[rt] = *(const half8*)&Ah[m*40 + quad*8];
                al[rt] = *(const half8*)&Al[m*40 + quad*8];
            }
            #pragma unroll
            for (int ct = 0; ct < 8; ++ct) {
                int c = ct*16 + xl;
                half8 bh = *(const half8*)&Bh[c*40 + quad*8];
                half8 bl = *(const half8*)&Bl[c*40 + quad*8];
                #pragma unroll
                for (int rt = 0; rt < 2; ++rt) {
                    a0[rt][ct] = __builtin_amdgcn_mfma_f32_16x16x32_f16(ah[rt], bh, a0[rt][ct], 0,0,0);
                    a1[rt][ct] = __builtin_amdgcn_mfma_f32_16x16x32_f16(al[rt], bh, a1[rt][ct], 0,0,0);
                    a1[rt][ct] = __builtin_amdgcn_mfma_f32_16x16x32_f16(ah[rt], bl, a1[rt][ct], 0,0,0);
                }
            }
            __syncthreads();
        }
        #pragma unroll
        for (int ct = 0; ct < 8; ++ct) {
            int colp = cb*128 + ct*16 + xl;
            int c = colp / 144, rr = colp % 144;
            int ta = rr >> 4, d = rr & 15;
            float kb = kernel_b[c*144 + d*9 + ta];
            #pragma unroll
            for (int rt = 0; rt < 2; ++rt)
                #pragma unroll
                for (int r = 0; r < 4; ++r) {
                    float v = a0[rt][ct][r] + a1[rt][ct][r]*(1.f/1024.f) + kb;
                    _Float16 h = (_Float16)v;
                    _Float16 lo = (_Float16)((v - (float)h)*1024.f);
                    union { _Float16 f; unsigned short u; } H, L;
                    H.f = h; L.f = lo;
                    size_t row = (size_t)rb*128 + wv*32 + rt*16 + quad*4 + r;
                    kernu[row*(size_t)KCOLS + colp] = ((unsigned)L.u << 16) | (unsigned)H.u;
                }
        }
    } else {
        // ---------------- giM ----------------
        int ob = b - 2785;                 // 0..1023
        int lblk = ob & 7, n = (ob >> 3) & 63, dir = ob >> 9;
        __shared__ float Ml[8][E_];
        for (int idx = tid; idx < 8*E_; idx += 256) {
            int r = idx >> 7, k = idx & 127;
            Ml[r][k] = M[(n*NL + lblk*8 + r)*E_ + k];
        }
        __syncthreads();
        const float4* W = (const float4*)(wiT4) + dir*32*384;
        for (int g = tid; g < 384; g += 256) {
            float acc[8];
            #pragma unroll
            for (int r = 0; r < 8; ++r) acc[r] = 0.f;
            for (int kq = 0; kq < 32; ++kq) {
                float4 w = W[kq*384 + g];
                #pragma unroll
                for (int r = 0; r < 8; ++r) {
                    float4 h = *(const float4*)&Ml[r][kq*4];
                    acc[r] += w.x*h.x + w.y*h.y + w.z*h.z + w.w*h.w;
                }
            }
            float bi = dir ? bib[g] : bif[g];
            #pragma unroll
            for (int r = 0; r < 8; ++r)
                giM[((dir*N_ + n)*NL + lblk*8 + r)*G3 + g] = acc[r] + bi;
        }
    }
}

// ---------------- MFMA GRU with LDS ring-buffer for giM rows ------------------------
__global__ __launch_bounds__(256, 2) void k_gru(const float* giM, const _Float16* WBpack,
                                                const float* bhf, const float* bhb,
                                                const float* beta_w, const float* beta_b,
                                                float* Ball) {
    int b = blockIdx.x;
    int x = b & 7, m = b >> 3;
    int pblk = m & 3;
    int s = x + 8*(m >> 2);
    int dir = s >> 6, n = s & 63;
    int tid = threadIdx.x;
    int w = tid >> 6;
    int lane = tid & 63;
    int quad = lane >> 4;
    int col  = lane & 15;

    __shared__ _Float16 Hhi[16*136];
    __shared__ _Float16 Hlo[16*136];
    __shared__ float    Hf[16*132];
    __shared__ float    bwT[4*132];
    __shared__ float    giR[32][G3];      // 48KB ring of giM rows
    for (int idx = tid; idx < 16*136; idx += 256) { Hhi[idx] = (_Float16)0.f; Hlo[idx] = (_Float16)0.f; }
    for (int idx = tid; idx < 16*132; idx += 256) Hf[idx] = 0.f;
    for (int idx = tid; idx < 512; idx += 256) { int k = idx >> 2, e = idx & 3; bwT[e*132 + k] = beta_w[k*NE + e]; }

    half8 WB[48];
    const half8* wsrc = (const half8*)(WBpack) + ((size_t)(dir*4 + w)*4)*12*64;
    #pragma unroll
    for (int f = 0; f < 48; ++f) WB[f] = wsrc[(size_t)f*64 + lane];

    const float* bh = dir ? bhb : bhf;
    float bhv[6];
    #pragma unroll
    for (int gt2 = 0; gt2 < 3; ++gt2) {
        bhv[gt2*2+0] = bh[gt2*128 + w*32 + col];
        bhv[gt2*2+1] = bh[gt2*128 + w*32 + col + 16];
    }
    const float* giBase = giM + (size_t)(dir*N_ + n)*NL*G3;

    // preload window for j=0
    {
        int start0 = dir ? ((pblk*16 + 63) & 63) : (pblk*16 & 63);
        for (int idx = tid; idx < 16*G3; idx += 256) {
            int sr = idx / G3, e = idx - sr*G3;
            int l = (start0 + sr) & 63;
            giR[l & 31][e] = giBase[(size_t)l*G3 + e];
        }
    }

    int bseq = tid >> 4, bsub = tid & 15, bee = bsub & 3, bpart = bsub >> 2;
    float bbias = beta_b[bee];
    __syncthreads();

    for (int j = 0; j < NL; ++j) {
        floatx4 C[6];
        #pragma unroll
        for (int reg = 0; reg < 4; ++reg) {
            int seq = quad*4 + reg;
            int p = pblk*16 + seq;
            int l = dir ? ((p + 63 - j) & 63) : ((p + j) & 63);
            const float* gl = &giR[l & 31][w*32 + col];
            #pragma unroll
            for (int gt2 = 0; gt2 < 2; ++gt2)
                #pragma unroll
                for (int isub = 0; isub < 2; ++isub)
                    C[gt2*2 + isub][reg] = gl[gt2*128 + isub*16] + bhv[gt2*2+isub];
            #pragma unroll
            for (int isub = 0; isub < 2; ++isub)
                C[4 + isub][reg] = bhv[4+isub];
        }
        #pragma unroll
        for (int kt = 0; kt < 4; ++kt) {
            int off = col*136 + kt*32 + quad*8;
            half8 ahi = *(const half8*)&Hhi[off];
            half8 alo = *(const half8*)&Hlo[off];
            #pragma unroll
            for (int nt = 0; nt < 6; ++nt) {
                half8 bhi2 = WB[kt*12 + nt];
                half8 blo2 = WB[kt*12 + 6 + nt];
                C[nt] = __builtin_amdgcn_mfma_f32_16x16x32_f16(ahi, bhi2, C[nt], 0,0,0);
                C[nt] = __builtin_amdgcn_mfma_f32_16x16x32_f16(alo, bhi2, C[nt], 0,0,0);
                C[nt] = __builtin_amdgcn_mfma_f32_16x16x32_f16(ahi, blo2, C[nt], 0,0,0);
            }
        }
        __syncthreads();

        if (j < 63) {
            int lnext = dir ? ((pblk*16 + 62 - j) & 63) : ((pblk*16 + j + 16) & 63);
            for (int idx = tid; idx < G3; idx += 256)
                giR[lnext & 31][idx] = giBase[(size_t)lnext*G3 + idx];
        }

        #pragma unroll
        for (int reg = 0; reg < 4; ++reg) {
            int seq = quad*4 + reg;
            int p = pblk*16 + seq;
            int l = dir ? ((p + 63 - j) & 63) : ((p + j) & 63);
            const float* gl2 = &giR[l & 31][256 + w*32 + col];
            #pragma unroll
            for (int isub = 0; isub < 2; ++isub) {
                int i = w*32 + isub*16 + col;
                float r  = fsig(C[isub][reg]);
                float z  = fsig(C[2 + isub][reg]);
                float nn = ftanh(gl2[isub*16] + r*C[4 + isub][reg]);
                float hold = Hf[seq*132 + i];
                float hnew = (1.f - z)*nn + z*hold;
                _Float16 hi = (_Float16)hnew;
                _Float16 lo = (_Float16)(hnew - (float)hi);
                Hf[seq*132 + i] = hnew;
                Hhi[seq*136 + i] = hi;
                Hlo[seq*136 + i] = lo;
            }
        }
        __syncthreads();

        {
            float acc = 0.f;
            const float* hrow = &Hf[bseq*132];
            const float* brow = &bwT[bee*132];
            #pragma unroll 8
            for (int kk = 0; kk < 32; ++kk) {
                int k2 = bpart + 4*kk;
                acc += hrow[k2]*brow[k2];
            }
            acc += __shfl_xor(acc, 4);
            acc += __shfl_xor(acc, 8);
            if (bpart == 0) {
                float bval = fsig(acc + bbias);
                int p = pblk*16 + bseq;
                Ball[((n*NL + p)*128 + 2*j + dir)*NE + bee] = bval;
            }
        }
    }
}

// ---------------- self-contained T-loop: 8 balanced waves ---------------------------
// phase C: w0-3 conv | w4 stager-lite (rows + P-compute, no obs) | w5-7 partA 3-way.
// B1.  seg2: w0-3 decision + cond stage_kern | w4 partB(t-1) | w5-7 obs(t+1) staging.
// B2.  obs buffer 1-par is first read in phase C(t+1), so B2 covers the staging.
__global__ __launch_bounds__(512, 1) void k_step(
    const float* obs, const unsigned int* kernu, const float* conv_bias,
    const float* zmp, const float* zip,
    const float* ump, const float* uip, const float* dmp, const float* dip,
    const float* zw, const float* aw, const float* ab,
    const float* uw, const float* dw, const float* cw, const float* cb,
    const float* amask, const float* Ball, const int* p0,
    float* out) {

    int n = blockIdx.x, tid = threadIdx.x;

    __shared__ __align__(16) _Float16 obs_h[2][OPL];     // padded [19][18+pad][OXP] hi
    __shared__ __align__(16) _Float16 obs_lo[2][OPL];    // lo * 1024
    __shared__ __align__(16) _Float16 klh[64*KPITCH];    // kern hi, [c][k' padded]
    __shared__ __align__(16) _Float16 kll[64*KPITCH];    // kern lo * 1024
    __shared__ float h1part[4][64];
    __shared__ __align__(16) float zml[2][HD];
    __shared__ __align__(16) float zil[2][HD];
    __shared__ __align__(16) float Pl[HD];
    __shared__ __align__(16) float Btmp[HD];             // Ball row scratch (wave 4)
    __shared__ __align__(16) float aml[2][16];
    __shared__ __align__(16) float uws[CH*NE];
    __shared__ __align__(16) float dws[CH*2];
    __shared__ float cbl[CH];
    __shared__ __align__(16) float umpl[4];
    __shared__ __align__(16) float uipl[4];
    __shared__ __align__(8)  float dmpl[2];
    __shared__ __align__(8)  float dipl[2];
    __shared__ float h1l[2][CH];
    __shared__ __align__(16) float z1l[HD];
    __shared__ float pla[128];
    __shared__ float pc[32];
    __shared__ float la[A_];
    __shared__ float lu[4];
    __shared__ float ld2[2];
    __shared__ float scv[1];
    __shared__ int   psint[2];

    int lane = tid & 63;
    int wv   = tid >> 6;
    int quad = lane >> 4;
    int xl   = lane & 15;

    // ---- kern row (interleaved uint) -> LDS hi/lo split (waves 0-3) ----
    auto stage_kern = [&](int prow) {
        if (tid < 256) {
            const uint4* src = (const uint4*)(kernu + (size_t)(n*NL + prow)*KCOLS);
            #pragma unroll
            for (int l = 0; l < 9; ++l) {
                int i = tid + l*256;            // 2304 uint4
                uint4 v = src[i];
                int e = i*4;
                int c = e / 144, k = e - c*144; // k 4-aligned within channel
                union { unsigned short u[4]; half4 h; } H, L;
                H.u[0] = (unsigned short)(v.x & 0xffffu); L.u[0] = (unsigned short)(v.x >> 16);
                H.u[1] = (unsigned short)(v.y & 0xffffu); L.u[1] = (unsigned short)(v.y >> 16);
                H.u[2] = (unsigned short)(v.z & 0xffffu); L.u[2] = (unsigned short)(v.z >> 16);
                H.u[3] = (unsigned short)(v.w & 0xffffu); L.u[3] = (unsigned short)(v.w >> 16);
                *(half4*)&klh[c*KPITCH + k] = H.h;
                *(half4*)&kll[c*KPITCH + k] = L.h;
            }
        }
    };

    // ---- tail partA (waves 5-7): z1/pla/pc thirds; identical per-entry arithmetic --
    auto tail_partA = [&](int tt, int bpar) {
        int w57 = wv - 5;                 // 0..2
        int ln  = lane;
        size_t ob2 = ((size_t)tt*N_ + n)*OUTW;
        int c8start = w57*3;
        int c8cnt = (w57 < 2) ? 3 : 2;    // {0-2},{3-5},{6-7}
        for (int c8i = 0; c8i < c8cnt; ++c8i) {
            int c8 = c8start + c8i;
            int h = c8*64 + ln;
            float a2 = zml[bpar][h] + zil[bpar][h];
            #pragma unroll 16
            for (int cc = 0; cc < CH; ++cc) a2 += h1l[bpar][cc]*zw[(E_ + cc)*HD + h];
            float v = fmaxf(a2, 0.f);
            z1l[h] = v;
            out[ob2 + 146 + h] = v;
        }
        int nparts = (w57 < 2) ? 3 : 2;   // pla parts {0-2},{3-5},{6-7}
        if (ln < nparts*16) {
            int a3 = ln & 15, part = w57*3 + (ln >> 4);
            float acc2 = 0.f;
            const float* z0 = z1l + part*64;
            #pragma unroll 16
            for (int h = 0; h < 64; ++h) acc2 += z0[h]*aw[(part*64 + h)*A_ + a3];
            pla[a3*8 + part] = acc2;
        }
        int pcStart = w57*11;             // pc {0-10},{11-21},{22-31}
        int pcCnt = (w57 == 2) ? 10 : 11;
        if (ln >= 48 && ln < 48 + pcCnt) {
            int e = pcStart + (ln - 48);
            float acc2 = 0.f;
            const float* z0 = z1l + e*16;
            #pragma unroll 16
            for (int h = 0; h < 16; ++h) acc2 += z0[h]*cw[e*16 + h];
            pc[e] = acc2;
        }
    };

    // ---- tail partB (wave 4, seg2): la/sc/softmax/out ----
    auto tail_partB = [&](int tt, int bpar) {
        int ln = lane;
        size_t ob2 = ((size_t)tt*N_ + n)*OUTW;
        if (ln < A_) {
            float acc2 = ab[ln];
            #pragma unroll
            for (int k = 0; k < 8; ++k) acc2 += pla[ln*8 + k];
            la[ln] = acc2;
        } else if (ln == 24) {
            float acc2 = cb[0];
            #pragma unroll
            for (int k = 0; k < 32; ++k) acc2 += pc[k];
            scv[0] = acc2;
        }
        if (ln == 0) {
            float mx = la[0];
            #pragma unroll
            for (int k2 = 1; k2 < A_; ++k2) mx = fmaxf(mx, la[k2]);
            float pr[A_]; float sum = 0.f;
            #pragma unroll
            for (int k2 = 0; k2 < A_; ++k2) { pr[k2] = expf(la[k2]-mx); sum += pr[k2]; }
            const float* am = &aml[bpar][0];
            float best = -1.f; int bi2 = 0;
            #pragma unroll
            for (int k2 = 0; k2 < A_; ++k2) {
                float v = pr[k2]/sum * am[k2];
                out[ob2 + 1 + k2] = v;
                if (v > best) { best = v; bi2 = k2; }
            }
            out[ob2 + 0] = (float)bi2;
        } else if (ln == 1) {
            out[ob2 + 659] = scv[0];
        }
    };

    // ---- obs(t+1) staging split across waves 5-7 (runs in seg2) ----
    auto stage_obs = [&](int tnext, int par_next) {
        int w57 = wv - 5;
        const float4* op4 = (const float4*)(obs + (size_t)(tnext*N_ + n)*D_*HW*HW);
        _Float16* dh = &obs_h[par_next][0];
        _Float16* dl = &obs_lo[par_next][0];
        for (int j = 0; j < 6; ++j) {
            int idx = j*192 + w57*64 + lane;
            if (idx < 1024) {
                float4 v = op4[idx];
                int d = idx >> 6, rem = idx & 63;
                int y = rem >> 2, xq = rem & 3;
                int base = (y+1)*OROW + (xq*4+1)*OXP + d;
                _Float16 h0=(_Float16)v.x, h1=(_Float16)v.y, h2=(_Float16)v.z, h3=(_Float16)v.w;
                dh[base+0*OXP] = h0; dl[base+0*OXP] = (_Float16)((v.x-(float)h0)*1024.f);
                dh[base+1*OXP] = h1; dl[base+1*OXP] = (_Float16)((v.y-(float)h1)*1024.f);
                dh[base+2*OXP] = h2; dl[base+2*OXP] = (_Float16)((v.z-(float)h2)*1024.f);
                dh[base+3*OXP] = h3; dl[base+3*OXP] = (_Float16)((v.w-(float)h3)*1024.f);
            }
        }
    };

    // ---------------- prologue ----------------
    int pcur = p0[n];
    {
        if (tid == 0) psint[1] = pcur;
        for (int i = tid; i < OPL; i += 512) {
            obs_h[0][i] = (_Float16)0.f; obs_h[1][i] = (_Float16)0.f;
            obs_lo[0][i] = (_Float16)0.f; obs_lo[1][i] = (_Float16)0.f;
        }
        for (int i = tid; i < 64*(KPITCH-144); i += 512) {
            int c = i / (KPITCH-144), k = 144 + i % (KPITCH-144);
            klh[c*KPITCH + k] = (_Float16)0.f;
            kll[c*KPITCH + k] = (_Float16)0.f;
        }
        if (tid < 64) cbl[tid] = conv_bias[tid];
        if (tid < 256) {
            uws[tid] = uw[(E_ + (tid >> 2))*NE + (tid & 3)];
            if (tid < 128) dws[tid] = dw[(E_ + (tid >> 1))*2 + (tid & 1)];
        }
    }
    __syncthreads();
    {
        if (tid < 256) {
            const float4* op4 = (const float4*)(obs + (size_t)(0*N_ + n)*D_*HW*HW);
            #pragma unroll
            for (int k4 = 0; k4 < 4; ++k4) {
                int idx = tid + k4*256;
                float4 v = op4[idx];
                int d = idx >> 6, rem = idx & 63;
                int y = rem >> 2, xq = rem & 3;
                int base = (y+1)*OROW + (xq*4+1)*OXP + d;
                _Float16 h0=(_Float16)v.x, h1=(_Float16)v.y, h2=(_Float16)v.z, h3=(_Float16)v.w;
                obs_h[0][base+0*OXP] = h0; obs_lo[0][base+0*OXP] = (_Float16)((v.x-(float)h0)*1024.f);
                obs_h[0][base+1*OXP] = h1; obs_lo[0][base+1*OXP] = (_Float16)((v.y-(float)h1)*1024.f);
                obs_h[0][base+2*OXP] = h2; obs_lo[0][base+2*OXP] = (_Float16)((v.z-(float)h2)*1024.f);
                obs_h[0][base+3*OXP] = h3; obs_lo[0][base+3*OXP] = (_Float16)((v.w-(float)h3)*1024.f);
            }
        }
        stage_kern(pcur);
    }
    __syncthreads();

    for (int t = 0; t < T_; ++t) {
        int par = t & 1;
        size_t ob = ((size_t)t*N_ + n)*OUTW;

        // ==== phase C: conv (w0-3) | stager-lite (w4) | partA(t-1) (w5-7) ==========
        if (wv < 4) {
            floatx4 a0[4][4];
            floatx4 a1[4][4];
            #pragma unroll
            for (int jm = 0; jm < 4; ++jm)
                #pragma unroll
                for (int ct = 0; ct < 4; ++ct) {
                    a0[jm][ct] = (floatx4){0.f,0.f,0.f,0.f};
                    a1[jm][ct] = (floatx4){0.f,0.f,0.f,0.f};
                }
            const _Float16* Oh = &obs_h[par][0];
            const _Float16* Ol = &obs_lo[par][0];
            #pragma unroll
            for (int kt = 0; kt < 5; ++kt) {
                int pi = kt*2 + (quad >> 1);
                int ky = (pi*11) >> 5;          // floor(pi/3), pi in 0..9
                int kx = pi - ky*3;
                int aoff = ky*OROW + kx*OXP + ((quad & 1) << 3) + xl*OXP;
                half8 ah[4], al[4];
                #pragma unroll
                for (int jm = 0; jm < 4; ++jm) {
                    int y = wv*4 + jm;
                    int o = aoff + y*OROW;
                    ah[jm] = *(const half8*)&Oh[o];
                    al[jm] = *(const half8*)&Ol[o];
                }
                #pragma unroll
                for (int ct = 0; ct < 4; ++ct) {
                    int bo = (ct*16 + xl)*KPITCH + kt*32 + quad*8;
                    half8 bh = *(const half8*)&klh[bo];
                    half8 bl = *(const half8*)&kll[bo];
                    #pragma unroll
                    for (int jm = 0; jm < 4; ++jm) {
                        a0[jm][ct] = __builtin_amdgcn_mfma_f32_16x16x32_f16(ah[jm], bh, a0[jm][ct], 0,0,0);
                        a1[jm][ct] = __builtin_amdgcn_mfma_f32_16x16x32_f16(al[jm], bh, a1[jm][ct], 0,0,0);
                        a1[jm][ct] = __builtin_amdgcn_mfma_f32_16x16x32_f16(ah[jm], bl, a1[jm][ct], 0,0,0);
                    }
                }
            }
            #pragma unroll
            for (int ct = 0; ct < 4; ++ct) {
                float bc = cbl[ct*16 + xl];
                float s = 0.f;
                #pragma unroll
                for (int jm = 0; jm < 4; ++jm) {
                    float sj = 0.f;
                    #pragma unroll
                    for (int r = 0; r < 4; ++r)
                        sj += fmaxf(a0[jm][ct][r] + a1[jm][ct][r]*(1.f/1024.f) + bc, 0.f);
                    s += sj;
                }
                s += __shfl_xor(s, 16);
                s += __shfl_xor(s, 32);
                if (quad == 0) h1part[wv][ct*16 + xl] = s;
            }
        } else if (wv == 4) {
            // stager-lite: p-dependent rows + stick-breaking P (no obs staging)
            int ln5 = lane;
            int pp = psint[1];
            const float4* Brow = (const float4*)(Ball + (size_t)(n*NL + pp)*128*NE);
            const float4* Zm   = (const float4*)(zmp  + (size_t)(n*NL + pp)*HD);
            const float4* Zi   = (const float4*)(zip  + (size_t)(t*N_ + n)*HD);
            #pragma unroll
            for (int k = 0; k < 2; ++k) {
                ((float4*)Btmp)[k*64 + ln5]         = Brow[k*64 + ln5];
                ((float4*)&zml[par][0])[k*64 + ln5] = Zm[k*64 + ln5];
                ((float4*)&zil[par][0])[k*64 + ln5] = Zi[k*64 + ln5];
            }
            if (ln5 < 4) {
                ((float4*)&aml[par][0])[ln5] = ((const float4*)(amask + ((size_t)t*N_ + n)*A_))[ln5];
            } else if (ln5 == 4) {
                *(float4*)umpl = *(const float4*)(ump + (size_t)(n*NL + pp)*NE);
            } else if (ln5 == 5) {
                *(float4*)uipl = *(const float4*)(uip + (size_t)(t*N_ + n)*NE);
            } else if (ln5 == 6) {
                *(float2*)dmpl = *(const float2*)(dmp + (size_t)(n*NL + pp)*2);
            } else if (ln5 == 7) {
                *(float2*)dipl = *(const float2*)(dip + (size_t)(t*N_ + n)*2);
            }
            // stick-breaking -> reordered Pl (bit-identical to old k_P)
            if (ln5 < NE) {
                int e = ln5;
                float c = 1.f;
                for (int j2 = 0; j2 < 128; ++j2) {
                    float bzv = (j2 == 0 || j2 == 127) ? 0.f : Btmp[j2*NE + e];
                    float bf = (j2 == 127) ? 1.f : bzv;
                    float pf = bf * c;
                    c *= (1.f - bzv);
                    int j = (j2 & 1) ? (63 - ((j2 - 1) >> 1)) : ((j2 >> 1) + 64);
                    Pl[j*NE + e] = pf;
                }
            }
        } else {
            if (t > 0) tail_partA(t - 1, 1 - par);
        }
        __syncthreads();   // B1

        // ==== seg2: decision (w0-3) | partB(t-1) (w4) | obs(t+1) staging (w5-7) ====
        if (wv < 4) {
            float hp = ((h1part[0][lane] + h1part[1][lane]) + h1part[2][lane]) + h1part[3][lane];
            h1l[par][lane] = hp;
            if (lane < 4) {
                float a2 = umpl[lane] + uipl[lane];
                #pragma unroll 16
                for (int cc = 0; cc < CH; ++cc) a2 += h1l[par][cc]*uws[cc*4 + lane];
                lu[lane] = a2;
            } else if (lane < 6) {
                int g = lane - 4;
                float a2 = dmpl[g] + dipl[g];
                #pragma unroll 16
                for (int cc = 0; cc < CH; ++cc) a2 += h1l[par][cc]*dws[cc*2 + g];
                ld2[g] = a2;
            }
            float l0 = lu[0], l1 = lu[1], l2 = lu[2], l3 = lu[3];
            float d0 = ld2[0], d1 = ld2[1];
            float mx = fmaxf(fmaxf(l0, l1), fmaxf(l2, l3));
            float e0u = expf(l0-mx), e1u = expf(l1-mx), e2u = expf(l2-mx), e3u = expf(l3-mx);
            float su = ((e0u + e1u) + e2u) + e3u;
            float uv0 = e0u/su, uv1 = e1u/su, uv2 = e2u/su, uv3 = e3u/su;
            int dg = (d1 > d0) ? 1 : 0;

            float4 Pva = ((const float4*)Pl)[lane];
            float4 Pvb = ((const float4*)Pl)[lane + 64];
            float va = Pva.x*uv0 + Pva.y*uv1 + Pva.z*uv2 + Pva.w*uv3;
            float vb = Pvb.x*uv0 + Pvb.y*uv1 + Pvb.z*uv2 + Pvb.w*uv3;
            if (tid < 64) {
                out[ob + 18 + lane] = va;
                out[ob + 82 + lane] = vb;
            }
            float bv = va; int bj = lane;
            if (vb > va) { bv = vb; bj = lane + 64; }
            #pragma unroll
            for (int off2 = 1; off2 < 64; off2 <<= 1) {
                float v2 = __shfl_xor(bv, off2);
                int   j2 = __shfl_xor(bj, off2);
                if (v2 > bv || (v2 == bv && j2 < bj)) { bv = v2; bj = j2; }
            }
            int dsel = dg ? bj : 64;
            int pn = pcur + dsel - 64;
            pn = pn < 0 ? 0 : (pn > 63 ? 63 : pn);
            if (tid == 0) {
                out[ob + 17]  = (float)dsel;
                out[ob + 658] = (float)pn;
                psint[1] = pn;             // publish for wave 4 (next phase C)
            } else if (tid == 2) {
                float mx2 = fmaxf(d0, d1);
                float q0 = expf(d0-mx2), q1 = expf(d1-mx2);
                float s2 = q0 + q1;
                out[ob + 660] = q0/s2;
                out[ob + 661] = q1/s2;
                out[ob + 662] = (float)dg;
            }
            if (t + 1 < T_ && pn != pcur) stage_kern(pn);
            pcur = pn;
        } else if (wv == 4) {
            if (t > 0) tail_partB(t - 1, 1 - par);
        } else {
            if (t + 1 < T_) stage_obs(t + 1, 1 - par);
        }
        __syncthreads();   // B2 (end of step)
    }

    // final tail for t = T-1 (parity 1): partA on waves 5-7, barrier, partB on wave 4
    if (wv >= 5) tail_partA(T_ - 1, 1);
    __syncthreads();
    if (wv == 4) tail_partB(T_ - 1, 1);
}

extern "C" void kernel_launch(void* const* d_in, const int* in_sizes, int n_in,
                              void* d_out, int out_size, void* d_ws, size_t ws_size,
                              hipStream_t stream) {
    (void)in_sizes; (void)n_in; (void)out_size; (void)ws_size;
    const int*   lines    = (const int*)  d_in[0];
    const float* obs      = (const float*)d_in[1];
    const float* invent   = (const float*)d_in[2];
    const int*   pa       = (const int*)  d_in[3];
    const float* amask    = (const float*)d_in[4];
    const int*   p0       = (const int*)  d_in[5];
    const float* emb_task = (const float*)d_in[6];
    const float* emb_low  = (const float*)d_in[7];
    const float* wi_f     = (const float*)d_in[8];
    const float* wh_f     = (const float*)d_in[9];
    const float* bi_f     = (const float*)d_in[10];
    const float* bh_f     = (const float*)d_in[11];
    const float* wi_b     = (const float*)d_in[12];
    const float* wh_b     = (const float*)d_in[13];
    const float* bi_b     = (const float*)d_in[14];
    const float* bh_b     = (const float*)d_in[15];
    const float* beta_w   = (const float*)d_in[16];
    const float* beta_b   = (const float*)d_in[17];
    const float* kernel_w = (const float*)d_in[18];
    const float* kernel_b = (const float*)d_in[19];
    const float* conv_b   = (const float*)d_in[20];
    const float* inv_w    = (const float*)d_in[21];
    const float* inv_b    = (const float*)d_in[22];
    const float* zw       = (const float*)d_in[23];
    const float* zb       = (const float*)d_in[24];
    const float* aw       = (const float*)d_in[25];
    const float* ab       = (const float*)d_in[26];
    const float* uw       = (const float*)d_in[27];
    const float* ub       = (const float*)d_in[28];
    const float* dw       = (const float*)d_in[29];
    const float* db       = (const float*)d_in[30];
    const float* cw       = (const float*)d_in[31];
    const float* cb       = (const float*)d_in[32];
    float* out = (float*)d_out;

    float* ws = (float*)d_ws;
    size_t off = 0;
    float* M        = ws + off; off += (size_t)N_*NL*E_;
    float* wiT4     = ws + off; off += 2*32*384*4;
    _Float16* WBpack = (_Float16*)(ws + off); off += (size_t)384*512/2;
    float* giM      = ws + off; off += (size_t)2*N_*NL*G3;
    float* Ball     = ws + off; off += (size_t)N_*NL*128*NE;
    float* Pall     = ws + off; off += (size_t)N_*NL*128*NE;   // unused (layout stability)
    float* inv_all  = ws + off; off += (size_t)T_*N_*RH;
    float* pa_all   = ws + off; off += (size_t)T_*N_*LE;
    unsigned int* kernu = (unsigned int*)(ws + off); off += (size_t)N_*NL*KCOLS; // 151 MB interleaved hi/lo
    float* h1_buf   = ws + off; off += (size_t)T_*N_*64;      // legacy, unused
    float* zmp      = ws + off; off += (size_t)N_*NL*HD;
    float* zip      = ws + off; off += (size_t)T_*N_*HD;
    float* ump      = ws + off; off += (size_t)N_*NL*NE;
    float* dmp      = ws + off; off += (size_t)N_*NL*2;
    float* uip      = ws + off; off += (size_t)T_*N_*NE;
    float* dip      = ws + off; off += (size_t)T_*N_*2;
    int*   flags    = (int*)(ws + off); off += 36992;
    int*   pflag    = flags + 32768;
    int*   p_arr    = pflag + 2112;
    float* kernel_wpT = ws + off; off += (size_t)E_*KCOLS;    // 4.7 MB, [colp][k]
    (void)h1_buf; (void)Pall;

    k_prep1<<<2225, 256, 0, stream>>>(lines, emb_task, M, wi_f, wi_b, wiT4,
                                      wh_f, wh_b, WBpack,
                                      invent, inv_w, inv_b, pa, emb_low, inv_all, pa_all,
                                      flags, kernel_w, kernel_wpT);
    k_mid<<<3809, 256, 0, stream>>>(M, inv_all, pa_all, zw, zb, uw, ub, dw, db,
                                    p0, p_arr, pflag,
                                    zmp, zip, ump, dmp, uip, dip,
                                    kernel_wpT, kernel_b, kernu,
                                    wiT4, bi_f, bi_b, giM);
    k_gru<<<512, 256, 0, stream>>>(giM, WBpack, bh_f, bh_b, beta_w, beta_b, Ball);

    k_step<<<64, 512, 0, stream>>>(obs, kernu, conv_b,
                                   zmp, zip, ump, uip, dmp, dip,
                                   zw, aw, ab, uw, dw, cw, cb,
                                   amask, Ball, p0, out);
}